// Round 1
// baseline (671.382 us; speedup 1.0000x reference)
//
#include <hip/hip_runtime.h>
#include <math.h>

#define C_      22      // NUM_CLASSES
#define SKIP_   20
#define NSTEP_  200
#define STEP_   4.0f
#define INL_T_  0.9f
#define LAB_T_  500
#define B_      2
#define H_      480
#define W_      640
#define HW_     (H_ * W_)       // 307200
#define P_      (HW_ / SKIP_)   // 15360

// -------- kernel 1: Hough voting (scatter atomics into B*C*H*W map) --------
__global__ __launch_bounds__(256) void vote_kernel(const int* __restrict__ label,
                                                   const float* __restrict__ vp,
                                                   float* __restrict__ hough) {
    int tid = blockIdx.x * 256 + threadIdx.x;
    if (tid >= B_ * P_) return;
    int b  = tid / P_;
    int pi = tid - b * P_;
    int idx = pi * SKIP_;
    int lab = label[b * HW_ + idx];
    if (lab <= 0) return;                      // fg only
    float ys = (float)(idx / W_);
    float xs = (float)(idx % W_);
    const float* s = vp + ((size_t)(b * HW_ + idx) * (C_ * 3)) + lab * 3;
    float dx = s[0], dy = s[1];
    // norm = sqrt(dx*dx + dy*dy) + 1e-9 — no fma, match XLA mul-then-add
    float nrm = sqrtf(__fadd_rn(__fmul_rn(dx, dx), __fmul_rn(dy, dy))) + 1e-9f;
    float dnx = dx / nrm, dny = dy / nrm;
    float* plane = hough + (size_t)(b * C_ + lab) * HW_;
    #pragma unroll 4
    for (int i = 0; i < NSTEP_; ++i) {
        float t = (float)(i + 1) * STEP_;
        float cx = __fadd_rn(xs, __fmul_rn(dnx, t));   // mul-then-add, no fma
        float cy = __fadd_rn(ys, __fmul_rn(dny, t));
        float cxr = rintf(cx);                          // round-half-even == jnp.round
        float cyr = rintf(cy);
        if (cxr >= 0.0f && cxr <= (float)(W_ - 1) && cyr >= 0.0f && cyr <= (float)(H_ - 1)) {
            int cxi = (int)cxr, cyi = (int)cyr;
            atomicAdd(&plane[cyi * W_ + cxi], 1.0f);
        }
    }
}

// -------- kernel 2: full-res label histogram --------
__global__ __launch_bounds__(256) void count_kernel(const int* __restrict__ label,
                                                    int* __restrict__ counts) {
    __shared__ int h[C_];
    const int bpb = HW_ / 256;     // 1200 blocks per batch
    int b   = blockIdx.x / bpb;
    int off = (blockIdx.x % bpb) * 256 + threadIdx.x;
    if (threadIdx.x < C_) h[threadIdx.x] = 0;
    __syncthreads();
    int lab = label[b * HW_ + off];
    atomicAdd(&h[lab], 1);
    __syncthreads();
    if (threadIdx.x < C_) {
        int v = h[threadIdx.x];
        if (v) atomicAdd(&counts[b * C_ + threadIdx.x], v);
    }
}

// -------- kernel 3: per-(b,c) argmax with first-occurrence tie-break --------
__global__ __launch_bounds__(256) void argmax_kernel(const float* __restrict__ hough,
                                                     float* __restrict__ vmax,
                                                     int* __restrict__ pk) {
    __shared__ float sv[256];
    __shared__ int   si[256];
    int bc = blockIdx.x;
    const float* plane = hough + (size_t)bc * HW_;
    float bv = -1.0f;   // hough >= 0 always
    int   bi = 0;
    for (int i = threadIdx.x; i < HW_; i += 256) {
        float v = plane[i];
        if (v > bv) { bv = v; bi = i; }        // strictly greater keeps earliest index
    }
    sv[threadIdx.x] = bv; si[threadIdx.x] = bi;
    __syncthreads();
    for (int s = 128; s > 0; s >>= 1) {
        if (threadIdx.x < s) {
            float ov = sv[threadIdx.x + s]; int oi = si[threadIdx.x + s];
            if (ov > sv[threadIdx.x] || (ov == sv[threadIdx.x] && oi < si[threadIdx.x])) {
                sv[threadIdx.x] = ov; si[threadIdx.x] = oi;
            }
        }
        __syncthreads();
    }
    if (threadIdx.x == 0) { vmax[bc] = sv[0]; pk[bc] = si[0]; }
}

// -------- kernel 4: inlier z/count accumulation --------
__global__ __launch_bounds__(256) void inlier_kernel(const int* __restrict__ label,
                                                     const float* __restrict__ vp,
                                                     const int* __restrict__ pk,
                                                     float* __restrict__ z_sum,
                                                     float* __restrict__ n_inl) {
    __shared__ float zs[C_];
    __shared__ float ns[C_];
    const int bpb = P_ / 256;      // 60 blocks per batch
    int b  = blockIdx.x / bpb;
    int pi = (blockIdx.x % bpb) * 256 + threadIdx.x;
    if (threadIdx.x < C_) { zs[threadIdx.x] = 0.0f; ns[threadIdx.x] = 0.0f; }
    __syncthreads();
    int idx = pi * SKIP_;
    int lab = label[b * HW_ + idx];
    if (lab > 0) {
        float ys = (float)(idx / W_);
        float xs = (float)(idx % W_);
        const float* s = vp + ((size_t)(b * HW_ + idx) * (C_ * 3)) + lab * 3;
        float dx = s[0], dy = s[1], z = s[2];
        float nrm = sqrtf(__fadd_rn(__fmul_rn(dx, dx), __fmul_rn(dy, dy))) + 1e-9f;
        float dnx = dx / nrm, dny = dy / nrm;
        int pkv = pk[b * C_ + lab];
        float pkx = (float)(pkv % W_), pky = (float)(pkv / W_);
        float dvx = __fsub_rn(pkx, xs), dvy = __fsub_rn(pky, ys);
        float nrm2 = sqrtf(__fadd_rn(__fmul_rn(dvx, dvx), __fmul_rn(dvy, dvy))) + 1e-9f;
        dvx /= nrm2; dvy /= nrm2;
        float dot = __fadd_rn(__fmul_rn(dnx, dvx), __fmul_rn(dny, dvy));
        if (dot > INL_T_) {
            atomicAdd(&zs[lab], z);
            atomicAdd(&ns[lab], 1.0f);
        }
    }
    __syncthreads();
    if (threadIdx.x < C_) {
        if (ns[threadIdx.x] != 0.0f) {
            atomicAdd(&z_sum[b * C_ + threadIdx.x], zs[threadIdx.x]);
            atomicAdd(&n_inl[b * C_ + threadIdx.x], ns[threadIdx.x]);
        }
    }
}

// -------- kernel 5: finalize rois + pose (44 outputs × 14 floats) --------
__global__ __launch_bounds__(64) void finalize_kernel(const int* __restrict__ counts,
                                                      const float* __restrict__ vmax,
                                                      const int* __restrict__ pk,
                                                      const float* __restrict__ z_sum,
                                                      const float* __restrict__ n_inl,
                                                      const float* __restrict__ extents,
                                                      const float* __restrict__ meta,
                                                      float* __restrict__ out) {
    int t = threadIdx.x;
    if (t >= B_ * C_) return;
    int b = t / C_, c = t % C_;
    float depth = z_sum[t] / fmaxf(n_inl[t], 1.0f);
    float z_safe = (fabsf(depth) > 0.001f) ? depth : 1.0f;
    float fx = meta[b * 48 + 0];
    float fy = meta[b * 48 + 4];
    const float* e = extents + c * 3;
    float diam = sqrtf(e[0]*e[0] + e[1]*e[1] + e[2]*e[2]);
    float vmask = (counts[t] >= LAB_T_ && c > 0) ? 1.0f : 0.0f;
    int pkv = pk[t];
    float pkx = (float)(pkv % W_), pky = (float)(pkv / W_);
    float half_w = ((0.5f * diam) * fx) / z_safe;
    float half_h = ((0.5f * diam) * fy) / z_safe;
    float* o = out + t * 14;
    o[0] = (float)b * vmask;
    o[1] = (float)c * vmask;
    o[2] = (pkx - half_w) * vmask;
    o[3] = (pky - half_h) * vmask;
    o[4] = (pkx + half_w) * vmask;
    o[5] = (pky + half_h) * vmask;
    o[6] = vmax[t] * vmask;
    const float* Ki = meta + b * 48 + 9;   // Kinv row-major 3x3
    float rx = Ki[0]*pkx + Ki[1]*pky + Ki[2];
    float ry = Ki[3]*pkx + Ki[4]*pky + Ki[5];
    float rz = Ki[6]*pkx + Ki[7]*pky + Ki[8];
    o[7]  = 1.0f * vmask;   // quat = [1,0,0,0] * vmask
    o[8]  = 0.0f;
    o[9]  = 0.0f;
    o[10] = 0.0f;
    o[11] = depth * rx * vmask;
    o[12] = depth * ry * vmask;
    o[13] = depth * rz * vmask;
}

extern "C" void kernel_launch(void* const* d_in, const int* in_sizes, int n_in,
                              void* d_out, int out_size, void* d_ws, size_t ws_size,
                              hipStream_t stream) {
    const int*   label   = (const int*)d_in[0];    // (B,H,W) int32
    const float* vp      = (const float*)d_in[1];  // (B,H,W,66) f32
    const float* extents = (const float*)d_in[2];  // (22,3) f32
    // d_in[3] = poses (unused)
    const float* meta    = (const float*)d_in[4];  // (B,48) f32
    float* out = (float*)d_out;                    // (B,C,14) = 616 f32

    // workspace layout (contiguous so one memset zeros everything)
    char* ws = (char*)d_ws;
    float* hough = (float*)ws;                                       // B*C*HW f32 = 54 MB
    size_t off = (size_t)B_ * C_ * HW_ * sizeof(float);
    int*   counts = (int*)(ws + off);  off += B_ * C_ * sizeof(int);
    float* z_sum  = (float*)(ws + off); off += B_ * C_ * sizeof(float);
    float* n_inl  = (float*)(ws + off); off += B_ * C_ * sizeof(float);
    size_t zero_bytes = off;                                         // all of the above need 0-init
    float* vmaxv = (float*)(ws + off);  off += B_ * C_ * sizeof(float);  // written, not accumulated
    int*   pk    = (int*)(ws + off);    off += B_ * C_ * sizeof(int);

    hipMemsetAsync(d_ws, 0, zero_bytes, stream);

    vote_kernel<<<(B_ * P_) / 256, 256, 0, stream>>>(label, vp, hough);
    count_kernel<<<(B_ * HW_) / 256, 256, 0, stream>>>(label, counts);
    argmax_kernel<<<B_ * C_, 256, 0, stream>>>(hough, vmaxv, pk);
    inlier_kernel<<<(B_ * P_) / 256, 256, 0, stream>>>(label, vp, pk, z_sum, n_inl);
    finalize_kernel<<<1, 64, 0, stream>>>(counts, vmaxv, pk, z_sum, n_inl, extents, meta, out);
}

// Round 2
// 342.293 us; speedup vs baseline: 1.9614x; 1.9614x over previous
//
#include <hip/hip_runtime.h>
#include <math.h>

#define C_      22      // NUM_CLASSES
#define SKIP_   20
#define NSTEP_  200
#define STEP_   4.0f
#define INL_T_  0.9f
#define LAB_T_  500
#define B_      2
#define H_      480
#define W_      640
#define HW_     (H_ * W_)       // 307200
#define P_      (HW_ / SKIP_)   // 15360
#define SUB_    8               // ray-step split per point
#define STEPS_PER_SUB_ (NSTEP_ / SUB_)   // 25
#define NPLANES_ (B_ * (C_ - 1))         // 42 live planes (c=0 is dead)
#define CHUNKS_ 25
#define CHUNK_F4_ (HW_ / CHUNKS_ / 4)    // 3072 float4 per chunk
#define F4_PER_THREAD_ (CHUNK_F4_ / 256) // 12

// -------- kernel 1: Hough voting, 8 threads per point --------
__global__ __launch_bounds__(256) void vote_kernel(const int* __restrict__ label,
                                                   const float* __restrict__ vp,
                                                   float* __restrict__ hough) {
    int tid = blockIdx.x * 256 + threadIdx.x;
    if (tid >= B_ * P_ * SUB_) return;
    int sub = tid & (SUB_ - 1);
    int pt  = tid >> 3;          // point id in [0, B_*P_)
    int b   = pt / P_;
    int pi  = pt - b * P_;
    int idx = pi * SKIP_;
    int lab = label[b * HW_ + idx];
    if (lab <= 0) return;
    float ys = (float)(idx / W_);
    float xs = (float)(idx % W_);
    const float* s = vp + ((size_t)(b * HW_ + idx) * (C_ * 3)) + lab * 3;
    float dx = s[0], dy = s[1];
    float nrm = sqrtf(__fadd_rn(__fmul_rn(dx, dx), __fmul_rn(dy, dy))) + 1e-9f;
    float dnx = dx / nrm, dny = dy / nrm;
    float* plane = hough + (size_t)(b * C_ + lab) * HW_;
    int i0 = sub * STEPS_PER_SUB_;
    #pragma unroll
    for (int j = 0; j < STEPS_PER_SUB_; ++j) {
        int i = i0 + j;
        float t = (float)(i + 1) * STEP_;
        float cx = __fadd_rn(xs, __fmul_rn(dnx, t));   // mul-then-add, no fma
        float cy = __fadd_rn(ys, __fmul_rn(dny, t));
        float cxr = rintf(cx);                          // round-half-even == jnp.round
        float cyr = rintf(cy);
        if (cxr >= 0.0f && cxr <= (float)(W_ - 1) && cyr >= 0.0f && cyr <= (float)(H_ - 1)) {
            int cxi = (int)cxr, cyi = (int)cyr;
            atomicAdd(&plane[cyi * W_ + cxi], 1.0f);
        }
    }
}

// -------- kernel 2: full-res label histogram --------
__global__ __launch_bounds__(256) void count_kernel(const int* __restrict__ label,
                                                    int* __restrict__ counts) {
    __shared__ int h[C_];
    const int bpb = HW_ / 256;
    int b   = blockIdx.x / bpb;
    int off = (blockIdx.x % bpb) * 256 + threadIdx.x;
    if (threadIdx.x < C_) h[threadIdx.x] = 0;
    __syncthreads();
    int lab = label[b * HW_ + off];
    atomicAdd(&h[lab], 1);
    __syncthreads();
    if (threadIdx.x < C_) {
        int v = h[threadIdx.x];
        if (v) atomicAdd(&counts[b * C_ + threadIdx.x], v);
    }
}

// -------- kernel 3a: per-(plane,chunk) partial argmax, float4 streaming --------
__global__ __launch_bounds__(256) void argmax1_kernel(const float* __restrict__ hough,
                                                      float* __restrict__ pval,
                                                      int* __restrict__ pidx) {
    __shared__ float sv[256];
    __shared__ int   si[256];
    int p     = blockIdx.x / CHUNKS_;   // live plane id 0..41
    int chunk = blockIdx.x % CHUNKS_;
    int b = p / (C_ - 1);
    int c = p % (C_ - 1) + 1;
    const float4* plane4 = (const float4*)(hough + (size_t)(b * C_ + c) * HW_);
    int base4 = chunk * CHUNK_F4_;
    float bv = -1.0f;
    int   bi = 0;
    #pragma unroll
    for (int j = 0; j < F4_PER_THREAD_; ++j) {
        int f4 = base4 + j * 256 + threadIdx.x;
        float4 v = plane4[f4];
        int i0 = f4 * 4;
        if (v.x > bv || (v.x == bv && i0     < bi)) { bv = v.x; bi = i0;     }
        if (v.y > bv || (v.y == bv && i0 + 1 < bi)) { bv = v.y; bi = i0 + 1; }
        if (v.z > bv || (v.z == bv && i0 + 2 < bi)) { bv = v.z; bi = i0 + 2; }
        if (v.w > bv || (v.w == bv && i0 + 3 < bi)) { bv = v.w; bi = i0 + 3; }
    }
    sv[threadIdx.x] = bv; si[threadIdx.x] = bi;
    __syncthreads();
    for (int s = 128; s > 0; s >>= 1) {
        if (threadIdx.x < s) {
            float ov = sv[threadIdx.x + s]; int oi = si[threadIdx.x + s];
            if (ov > sv[threadIdx.x] || (ov == sv[threadIdx.x] && oi < si[threadIdx.x])) {
                sv[threadIdx.x] = ov; si[threadIdx.x] = oi;
            }
        }
        __syncthreads();
    }
    if (threadIdx.x == 0) { pval[blockIdx.x] = sv[0]; pidx[blockIdx.x] = si[0]; }
}

// -------- kernel 3b: reduce 25 partials per plane --------
__global__ __launch_bounds__(32) void argmax2_kernel(const float* __restrict__ pval,
                                                     const int* __restrict__ pidx,
                                                     float* __restrict__ vmax,
                                                     int* __restrict__ pk) {
    __shared__ float sv[32];
    __shared__ int   si[32];
    int p = blockIdx.x;          // live plane 0..41
    int t = threadIdx.x;
    if (t < CHUNKS_) { sv[t] = pval[p * CHUNKS_ + t]; si[t] = pidx[p * CHUNKS_ + t]; }
    else             { sv[t] = -1.0f; si[t] = 0x7fffffff; }
    __syncthreads();
    for (int s = 16; s > 0; s >>= 1) {
        if (t < s) {
            float ov = sv[t + s]; int oi = si[t + s];
            if (ov > sv[t] || (ov == sv[t] && oi < si[t])) { sv[t] = ov; si[t] = oi; }
        }
        __syncthreads();
    }
    if (t == 0) {
        int b = p / (C_ - 1);
        int c = p % (C_ - 1) + 1;
        vmax[b * C_ + c] = sv[0];
        pk[b * C_ + c]   = si[0];
    }
}

// -------- kernel 4: inlier z/count accumulation --------
__global__ __launch_bounds__(256) void inlier_kernel(const int* __restrict__ label,
                                                     const float* __restrict__ vp,
                                                     const int* __restrict__ pk,
                                                     float* __restrict__ z_sum,
                                                     float* __restrict__ n_inl) {
    __shared__ float zs[C_];
    __shared__ float ns[C_];
    const int bpb = P_ / 256;
    int b  = blockIdx.x / bpb;
    int pi = (blockIdx.x % bpb) * 256 + threadIdx.x;
    if (threadIdx.x < C_) { zs[threadIdx.x] = 0.0f; ns[threadIdx.x] = 0.0f; }
    __syncthreads();
    int idx = pi * SKIP_;
    int lab = label[b * HW_ + idx];
    if (lab > 0) {
        float ys = (float)(idx / W_);
        float xs = (float)(idx % W_);
        const float* s = vp + ((size_t)(b * HW_ + idx) * (C_ * 3)) + lab * 3;
        float dx = s[0], dy = s[1], z = s[2];
        float nrm = sqrtf(__fadd_rn(__fmul_rn(dx, dx), __fmul_rn(dy, dy))) + 1e-9f;
        float dnx = dx / nrm, dny = dy / nrm;
        int pkv = pk[b * C_ + lab];
        float pkx = (float)(pkv % W_), pky = (float)(pkv / W_);
        float dvx = __fsub_rn(pkx, xs), dvy = __fsub_rn(pky, ys);
        float nrm2 = sqrtf(__fadd_rn(__fmul_rn(dvx, dvx), __fmul_rn(dvy, dvy))) + 1e-9f;
        dvx /= nrm2; dvy /= nrm2;
        float dot = __fadd_rn(__fmul_rn(dnx, dvx), __fmul_rn(dny, dvy));
        if (dot > INL_T_) {
            atomicAdd(&zs[lab], z);
            atomicAdd(&ns[lab], 1.0f);
        }
    }
    __syncthreads();
    if (threadIdx.x < C_) {
        if (ns[threadIdx.x] != 0.0f) {
            atomicAdd(&z_sum[b * C_ + threadIdx.x], zs[threadIdx.x]);
            atomicAdd(&n_inl[b * C_ + threadIdx.x], ns[threadIdx.x]);
        }
    }
}

// -------- kernel 5: finalize rois + pose --------
__global__ __launch_bounds__(64) void finalize_kernel(const int* __restrict__ counts,
                                                      const float* __restrict__ vmax,
                                                      const int* __restrict__ pk,
                                                      const float* __restrict__ z_sum,
                                                      const float* __restrict__ n_inl,
                                                      const float* __restrict__ extents,
                                                      const float* __restrict__ meta,
                                                      float* __restrict__ out) {
    int t = threadIdx.x;
    if (t >= B_ * C_) return;
    int b = t / C_, c = t % C_;
    float* o = out + t * 14;
    bool valid = (counts[t] >= LAB_T_) && (c > 0);
    if (!valid) {
        #pragma unroll
        for (int k = 0; k < 14; ++k) o[k] = 0.0f;
        return;
    }
    float depth = z_sum[t] / fmaxf(n_inl[t], 1.0f);
    float z_safe = (fabsf(depth) > 0.001f) ? depth : 1.0f;
    float fx = meta[b * 48 + 0];
    float fy = meta[b * 48 + 4];
    const float* e = extents + c * 3;
    float diam = sqrtf(e[0]*e[0] + e[1]*e[1] + e[2]*e[2]);
    int pkv = pk[t];
    float pkx = (float)(pkv % W_), pky = (float)(pkv / W_);
    float half_w = ((0.5f * diam) * fx) / z_safe;
    float half_h = ((0.5f * diam) * fy) / z_safe;
    o[0] = (float)b;
    o[1] = (float)c;
    o[2] = pkx - half_w;
    o[3] = pky - half_h;
    o[4] = pkx + half_w;
    o[5] = pky + half_h;
    o[6] = vmax[t];
    const float* Ki = meta + b * 48 + 9;   // Kinv row-major 3x3
    float rx = Ki[0]*pkx + Ki[1]*pky + Ki[2];
    float ry = Ki[3]*pkx + Ki[4]*pky + Ki[5];
    float rz = Ki[6]*pkx + Ki[7]*pky + Ki[8];
    o[7]  = 1.0f;
    o[8]  = 0.0f;
    o[9]  = 0.0f;
    o[10] = 0.0f;
    o[11] = depth * rx;
    o[12] = depth * ry;
    o[13] = depth * rz;
}

extern "C" void kernel_launch(void* const* d_in, const int* in_sizes, int n_in,
                              void* d_out, int out_size, void* d_ws, size_t ws_size,
                              hipStream_t stream) {
    const int*   label   = (const int*)d_in[0];    // (B,H,W) int32
    const float* vp      = (const float*)d_in[1];  // (B,H,W,66) f32
    const float* extents = (const float*)d_in[2];  // (22,3) f32
    const float* meta    = (const float*)d_in[4];  // (B,48) f32
    float* out = (float*)d_out;                    // (B,C,14) = 616 f32

    char* ws = (char*)d_ws;
    float* hough = (float*)ws;                                       // B*C*HW f32 = 54 MB
    size_t off = (size_t)B_ * C_ * HW_ * sizeof(float);
    int*   counts = (int*)(ws + off);  off += B_ * C_ * sizeof(int);
    float* z_sum  = (float*)(ws + off); off += B_ * C_ * sizeof(float);
    float* n_inl  = (float*)(ws + off); off += B_ * C_ * sizeof(float);
    size_t zero_bytes = off;                                         // region needing 0-init
    float* vmaxv = (float*)(ws + off);  off += B_ * C_ * sizeof(float);
    int*   pk    = (int*)(ws + off);    off += B_ * C_ * sizeof(int);
    float* pval  = (float*)(ws + off);  off += NPLANES_ * CHUNKS_ * sizeof(float);
    int*   pidx  = (int*)(ws + off);    off += NPLANES_ * CHUNKS_ * sizeof(int);

    hipMemsetAsync(d_ws, 0, zero_bytes, stream);

    vote_kernel<<<(B_ * P_ * SUB_) / 256, 256, 0, stream>>>(label, vp, hough);
    count_kernel<<<(B_ * HW_) / 256, 256, 0, stream>>>(label, counts);
    argmax1_kernel<<<NPLANES_ * CHUNKS_, 256, 0, stream>>>(hough, pval, pidx);
    argmax2_kernel<<<NPLANES_, 32, 0, stream>>>(pval, pidx, vmaxv, pk);
    inlier_kernel<<<(B_ * P_) / 256, 256, 0, stream>>>(label, vp, pk, z_sum, n_inl);
    finalize_kernel<<<1, 64, 0, stream>>>(counts, vmaxv, pk, z_sum, n_inl, extents, meta, out);
}

// Round 3
// 309.632 us; speedup vs baseline: 2.1683x; 1.1055x over previous
//
#include <hip/hip_runtime.h>
#include <math.h>

#define C_      22      // NUM_CLASSES
#define SKIP_   20
#define NSTEP_  200
#define STEP_   4.0f
#define INL_T_  0.9f
#define LAB_T_  500
#define B_      2
#define H_      480
#define W_      640
#define HW_     (H_ * W_)       // 307200
#define HWW_    (HW_ / 2)       // 153600 packed u16x2 words per plane
#define P_      (HW_ / SKIP_)   // 15360
#define SUB_    20              // ray-step split per point
#define STEPS_PER_SUB_ (NSTEP_ / SUB_)   // 10
#define NPLANES_ (B_ * (C_ - 1))         // 42 live planes (c=0 is dead)
#define CHUNKS_ 25
#define CELLS_PER_CHUNK_ (HW_ / CHUNKS_)         // 12288
#define U4_PER_CHUNK_ (CELLS_PER_CHUNK_ / 8)     // 1536 uint4 (8 cells each)
#define U4_PER_THREAD_ (U4_PER_CHUNK_ / 256)     // 6

#define VOTE_BLOCKS_  ((B_ * P_ * SUB_) / 256)   // 2400
#define COUNT_BLOCKS_ ((B_ * HW_) / 256)         // 2400

// -------- fused kernel: blocks [0,VOTE_BLOCKS_) vote, rest count --------
__global__ __launch_bounds__(256) void vote_count_kernel(const int* __restrict__ label,
                                                         const float* __restrict__ vp,
                                                         unsigned int* __restrict__ hough_w,
                                                         int* __restrict__ counts) {
    if (blockIdx.x < VOTE_BLOCKS_) {
        // ---- vote: 20 sub-threads per point, 10 ray steps each ----
        int tid = blockIdx.x * 256 + threadIdx.x;
        int pt  = tid / SUB_;
        int sub = tid - pt * SUB_;
        int b   = pt / P_;
        int pi  = pt - b * P_;
        int idx = pi * SKIP_;
        int lab = label[b * HW_ + idx];
        if (lab <= 0) return;
        float ys = (float)(idx / W_);
        float xs = (float)(idx % W_);
        const float* s = vp + ((size_t)(b * HW_ + idx) * (C_ * 3)) + lab * 3;
        float dx = s[0], dy = s[1];
        float nrm = sqrtf(__fadd_rn(__fmul_rn(dx, dx), __fmul_rn(dy, dy))) + 1e-9f;
        float dnx = dx / nrm, dny = dy / nrm;
        unsigned int* plane = hough_w + (size_t)(b * C_ + lab) * HWW_;
        int i0 = sub * STEPS_PER_SUB_;
        #pragma unroll
        for (int j = 0; j < STEPS_PER_SUB_; ++j) {
            int i = i0 + j;
            float t = (float)(i + 1) * STEP_;
            float cx = __fadd_rn(xs, __fmul_rn(dnx, t));   // mul-then-add, no fma
            float cy = __fadd_rn(ys, __fmul_rn(dny, t));
            float cxr = rintf(cx);                          // round-half-even == jnp.round
            float cyr = rintf(cy);
            if (cxr >= 0.0f && cxr <= (float)(W_ - 1) && cyr >= 0.0f && cyr <= (float)(H_ - 1)) {
                int cell = (int)cyr * W_ + (int)cxr;
                atomicAdd(&plane[cell >> 1], 1u << ((cell & 1) * 16));
            }
        }
    } else {
        // ---- label histogram ----
        __shared__ int h[C_];
        int cb  = blockIdx.x - VOTE_BLOCKS_;
        const int bpb = HW_ / 256;
        int b   = cb / bpb;
        int off = (cb % bpb) * 256 + threadIdx.x;
        if (threadIdx.x < C_) h[threadIdx.x] = 0;
        __syncthreads();
        int lab = label[b * HW_ + off];
        atomicAdd(&h[lab], 1);
        __syncthreads();
        if (threadIdx.x < C_) {
            int v = h[threadIdx.x];
            if (v) atomicAdd(&counts[b * C_ + threadIdx.x], v);
        }
    }
}

// -------- argmax over packed u16 planes, merged via u64 atomicMax --------
// key = (count << 32) | (0xFFFFFFFF - idx): max key == max count, then min idx.
__global__ __launch_bounds__(256) void argmax1_kernel(const unsigned int* __restrict__ hough_w,
                                                      unsigned long long* __restrict__ key) {
    __shared__ int sv[256];
    __shared__ int si[256];
    int p     = blockIdx.x / CHUNKS_;   // live plane id 0..41
    int chunk = blockIdx.x % CHUNKS_;
    int b = p / (C_ - 1);
    int c = p % (C_ - 1) + 1;
    const uint4* plane4 = (const uint4*)(hough_w + (size_t)(b * C_ + c) * HWW_);
    int base4 = chunk * U4_PER_CHUNK_;
    int bv = -1;
    int bi = 0;
    #pragma unroll
    for (int j = 0; j < U4_PER_THREAD_; ++j) {
        int f4 = base4 + j * 256 + threadIdx.x;
        uint4 w = plane4[f4];
        int i0 = f4 * 8;   // cell index of w.x low half
        int v;
        v = (int)(w.x & 0xFFFFu); if (v > bv) { bv = v; bi = i0;     }
        v = (int)(w.x >> 16);     if (v > bv) { bv = v; bi = i0 + 1; }
        v = (int)(w.y & 0xFFFFu); if (v > bv) { bv = v; bi = i0 + 2; }
        v = (int)(w.y >> 16);     if (v > bv) { bv = v; bi = i0 + 3; }
        v = (int)(w.z & 0xFFFFu); if (v > bv) { bv = v; bi = i0 + 4; }
        v = (int)(w.z >> 16);     if (v > bv) { bv = v; bi = i0 + 5; }
        v = (int)(w.w & 0xFFFFu); if (v > bv) { bv = v; bi = i0 + 6; }
        v = (int)(w.w >> 16);     if (v > bv) { bv = v; bi = i0 + 7; }
    }
    sv[threadIdx.x] = bv; si[threadIdx.x] = bi;
    __syncthreads();
    for (int s = 128; s > 0; s >>= 1) {
        if (threadIdx.x < s) {
            int ov = sv[threadIdx.x + s], oi = si[threadIdx.x + s];
            if (ov > sv[threadIdx.x] || (ov == sv[threadIdx.x] && oi < si[threadIdx.x])) {
                sv[threadIdx.x] = ov; si[threadIdx.x] = oi;
            }
        }
        __syncthreads();
    }
    if (threadIdx.x == 0) {
        unsigned long long k = ((unsigned long long)(unsigned int)sv[0] << 32)
                             | (unsigned long long)(0xFFFFFFFFu - (unsigned int)si[0]);
        atomicMax(&key[b * C_ + c], k);
    }
}

// -------- inlier z/count accumulation --------
__global__ __launch_bounds__(256) void inlier_kernel(const int* __restrict__ label,
                                                     const float* __restrict__ vp,
                                                     const unsigned long long* __restrict__ key,
                                                     float* __restrict__ z_sum,
                                                     float* __restrict__ n_inl) {
    __shared__ float zs[C_];
    __shared__ float ns[C_];
    const int bpb = P_ / 256;
    int b  = blockIdx.x / bpb;
    int pi = (blockIdx.x % bpb) * 256 + threadIdx.x;
    if (threadIdx.x < C_) { zs[threadIdx.x] = 0.0f; ns[threadIdx.x] = 0.0f; }
    __syncthreads();
    int idx = pi * SKIP_;
    int lab = label[b * HW_ + idx];
    if (lab > 0) {
        float ys = (float)(idx / W_);
        float xs = (float)(idx % W_);
        const float* s = vp + ((size_t)(b * HW_ + idx) * (C_ * 3)) + lab * 3;
        float dx = s[0], dy = s[1], z = s[2];
        float nrm = sqrtf(__fadd_rn(__fmul_rn(dx, dx), __fmul_rn(dy, dy))) + 1e-9f;
        float dnx = dx / nrm, dny = dy / nrm;
        unsigned long long k = key[b * C_ + lab];
        int pkv = (int)(0xFFFFFFFFu - (unsigned int)(k & 0xFFFFFFFFull));
        float pkx = (float)(pkv % W_), pky = (float)(pkv / W_);
        float dvx = __fsub_rn(pkx, xs), dvy = __fsub_rn(pky, ys);
        float nrm2 = sqrtf(__fadd_rn(__fmul_rn(dvx, dvx), __fmul_rn(dvy, dvy))) + 1e-9f;
        dvx /= nrm2; dvy /= nrm2;
        float dot = __fadd_rn(__fmul_rn(dnx, dvx), __fmul_rn(dny, dvy));
        if (dot > INL_T_) {
            atomicAdd(&zs[lab], z);
            atomicAdd(&ns[lab], 1.0f);
        }
    }
    __syncthreads();
    if (threadIdx.x < C_) {
        if (ns[threadIdx.x] != 0.0f) {
            atomicAdd(&z_sum[b * C_ + threadIdx.x], zs[threadIdx.x]);
            atomicAdd(&n_inl[b * C_ + threadIdx.x], ns[threadIdx.x]);
        }
    }
}

// -------- finalize rois + pose --------
__global__ __launch_bounds__(64) void finalize_kernel(const int* __restrict__ counts,
                                                      const unsigned long long* __restrict__ key,
                                                      const float* __restrict__ z_sum,
                                                      const float* __restrict__ n_inl,
                                                      const float* __restrict__ extents,
                                                      const float* __restrict__ meta,
                                                      float* __restrict__ out) {
    int t = threadIdx.x;
    if (t >= B_ * C_) return;
    int b = t / C_, c = t % C_;
    float* o = out + t * 14;
    bool valid = (counts[t] >= LAB_T_) && (c > 0);
    if (!valid) {
        #pragma unroll
        for (int k = 0; k < 14; ++k) o[k] = 0.0f;
        return;
    }
    float depth = z_sum[t] / fmaxf(n_inl[t], 1.0f);
    float z_safe = (fabsf(depth) > 0.001f) ? depth : 1.0f;
    float fx = meta[b * 48 + 0];
    float fy = meta[b * 48 + 4];
    const float* e = extents + c * 3;
    float diam = sqrtf(e[0]*e[0] + e[1]*e[1] + e[2]*e[2]);
    unsigned long long k = key[t];
    float vmax = (float)(unsigned int)(k >> 32);
    int pkv = (int)(0xFFFFFFFFu - (unsigned int)(k & 0xFFFFFFFFull));
    float pkx = (float)(pkv % W_), pky = (float)(pkv / W_);
    float half_w = ((0.5f * diam) * fx) / z_safe;
    float half_h = ((0.5f * diam) * fy) / z_safe;
    o[0] = (float)b;
    o[1] = (float)c;
    o[2] = pkx - half_w;
    o[3] = pky - half_h;
    o[4] = pkx + half_w;
    o[5] = pky + half_h;
    o[6] = vmax;
    const float* Ki = meta + b * 48 + 9;   // Kinv row-major 3x3
    float rx = Ki[0]*pkx + Ki[1]*pky + Ki[2];
    float ry = Ki[3]*pkx + Ki[4]*pky + Ki[5];
    float rz = Ki[6]*pkx + Ki[7]*pky + Ki[8];
    o[7]  = 1.0f;
    o[8]  = 0.0f;
    o[9]  = 0.0f;
    o[10] = 0.0f;
    o[11] = depth * rx;
    o[12] = depth * ry;
    o[13] = depth * rz;
}

extern "C" void kernel_launch(void* const* d_in, const int* in_sizes, int n_in,
                              void* d_out, int out_size, void* d_ws, size_t ws_size,
                              hipStream_t stream) {
    const int*   label   = (const int*)d_in[0];    // (B,H,W) int32
    const float* vp      = (const float*)d_in[1];  // (B,H,W,66) f32
    const float* extents = (const float*)d_in[2];  // (22,3) f32
    const float* meta    = (const float*)d_in[4];  // (B,48) f32
    float* out = (float*)d_out;                    // (B,C,14) = 616 f32

    char* ws = (char*)d_ws;
    unsigned int* hough_w = (unsigned int*)ws;                 // B*C*HW/2 u32 = 27 MB
    size_t off = (size_t)B_ * C_ * HWW_ * sizeof(unsigned int);
    unsigned long long* key = (unsigned long long*)(ws + off); off += B_ * C_ * sizeof(unsigned long long);
    int*   counts = (int*)(ws + off);   off += B_ * C_ * sizeof(int);
    float* z_sum  = (float*)(ws + off); off += B_ * C_ * sizeof(float);
    float* n_inl  = (float*)(ws + off); off += B_ * C_ * sizeof(float);
    size_t zero_bytes = off;

    hipMemsetAsync(d_ws, 0, zero_bytes, stream);

    vote_count_kernel<<<VOTE_BLOCKS_ + COUNT_BLOCKS_, 256, 0, stream>>>(label, vp, hough_w, counts);
    argmax1_kernel<<<NPLANES_ * CHUNKS_, 256, 0, stream>>>(hough_w, key);
    inlier_kernel<<<(B_ * P_) / 256, 256, 0, stream>>>(label, vp, key, z_sum, n_inl);
    finalize_kernel<<<1, 64, 0, stream>>>(counts, key, z_sum, n_inl, extents, meta, out);
}

// Round 4
// 288.149 us; speedup vs baseline: 2.3300x; 1.0746x over previous
//
#include <hip/hip_runtime.h>
#include <math.h>

#define C_      22      // NUM_CLASSES
#define SKIP_   20
#define NSTEP_  200
#define STEP_   4.0f
#define INL_T_  0.9f
#define LAB_T_  500
#define B_      2
#define H_      480
#define W_      640
#define HW_     (H_ * W_)       // 307200
#define P_      (HW_ / SKIP_)   // 15360

#define TS_       64            // spatial tile side
#define TILES_X_  (W_ / TS_)    // 10
#define TILES_Y_  (H_ / TS_)    // 8 (480/64 = 7.5 -> careful!)
// 480/64 = 7.5 — NOT integer. Use 10x8 tiles of 64x64 covering 640x512 (y tiles 0..7, last covers 448..511; cyr<=479 keeps it in-bounds logically).
#define NTILES_Y_ 8
#define NTILES_   (TILES_X_ * NTILES_Y_)   // 80
#define NPLANES_  (B_ * (C_ - 1))          // 42 live planes (c=0 dead)
#define NPT_      (NPLANES_ * NTILES_)     // 3360 plane-tiles
#define CAP_      1024                     // records per plane-tile

#define SUB_A_    4                        // ray segments per point in pass A
#define SEG_LEN_  (NSTEP_ / SUB_A_)        // 50
#define PA_BLOCKS_    ((B_ * P_ * SUB_A_) / 256)  // 480
#define COUNT_BLOCKS_ ((B_ * HW_) / 256)          // 2400

// -------- pass A: ray->tile-run binning (+ fused label histogram) --------
__device__ __forceinline__ void emit_run(unsigned int* cnt, uint4* lists, int pt,
                                         int xi, int yi, int i0, int i1,
                                         float dnx, float dny) {
    unsigned slot = atomicAdd(&cnt[pt], 1u);
    if (slot < CAP_) {
        uint4 r;
        r.x = (unsigned)xi | ((unsigned)yi << 16);
        r.y = (unsigned)i0 | ((unsigned)i1 << 8);
        r.z = __float_as_uint(dnx);
        r.w = __float_as_uint(dny);
        lists[(size_t)pt * CAP_ + slot] = r;
    }
}

__global__ __launch_bounds__(256) void binray_count_kernel(const int* __restrict__ label,
                                                           const float* __restrict__ vp,
                                                           unsigned int* __restrict__ cnt,
                                                           uint4* __restrict__ lists,
                                                           int* __restrict__ counts) {
    if (blockIdx.x < PA_BLOCKS_) {
        int tid = blockIdx.x * 256 + threadIdx.x;   // 0 .. B_*P_*SUB_A_-1
        int pt  = tid >> 2;                          // point id
        int sub = tid & 3;
        int b   = pt / P_;
        int pi  = pt - b * P_;
        int idx = pi * SKIP_;
        int lab = label[b * HW_ + idx];
        if (lab <= 0) return;
        int xi = idx % W_, yi = idx / W_;
        float xs = (float)xi, ys = (float)yi;
        const float* s = vp + ((size_t)(b * HW_ + idx) * (C_ * 3)) + lab * 3;
        float dx = s[0], dy = s[1];
        float nrm = sqrtf(__fadd_rn(__fmul_rn(dx, dx), __fmul_rn(dy, dy))) + 1e-9f;
        float dnx = dx / nrm, dny = dy / nrm;
        int base = (b * (C_ - 1) + (lab - 1)) * NTILES_;
        int curTile = -1, runStart = 0;
        int iBeg = sub * SEG_LEN_, iEnd = iBeg + SEG_LEN_;
        for (int i = iBeg; i < iEnd; ++i) {
            float t = (float)(i + 1) * STEP_;
            float cx = __fadd_rn(xs, __fmul_rn(dnx, t));   // mul-then-add, no fma
            float cy = __fadd_rn(ys, __fmul_rn(dny, t));
            float cxr = rintf(cx);                          // round-half-even == jnp.round
            float cyr = rintf(cy);
            int tile = -1;
            if (cxr >= 0.0f && cxr <= (float)(W_ - 1) && cyr >= 0.0f && cyr <= (float)(H_ - 1))
                tile = (((int)cyr) >> 6) * TILES_X_ + (((int)cxr) >> 6);
            if (tile != curTile) {
                if (curTile >= 0)
                    emit_run(cnt, lists, base + curTile, xi, yi, runStart, i - 1, dnx, dny);
                curTile = tile;
                runStart = i;
            }
        }
        if (curTile >= 0)
            emit_run(cnt, lists, base + curTile, xi, yi, runStart, iEnd - 1, dnx, dny);
    } else {
        // ---- label histogram ----
        __shared__ int h[C_];
        int cb  = blockIdx.x - PA_BLOCKS_;
        const int bpb = HW_ / 256;
        int b   = cb / bpb;
        int off = (cb % bpb) * 256 + threadIdx.x;
        if (threadIdx.x < C_) h[threadIdx.x] = 0;
        __syncthreads();
        int lab = label[b * HW_ + off];
        atomicAdd(&h[lab], 1);
        __syncthreads();
        if (threadIdx.x < C_) {
            int v = h[threadIdx.x];
            if (v) atomicAdd(&counts[b * C_ + threadIdx.x], v);
        }
    }
}

// -------- pass B: LDS tile rasterize + per-tile argmax + global key merge --------
// key = (count << 32) | (0xFFFFFFFF - idx): max key == max count, tie -> min idx.
__global__ __launch_bounds__(256) void raster_argmax_kernel(const unsigned int* __restrict__ cnt,
                                                            const uint4* __restrict__ lists,
                                                            unsigned long long* __restrict__ key) {
    __shared__ unsigned int tile[TS_ * TS_];   // 16 KB
    __shared__ unsigned int sv[256];
    __shared__ int          si[256];
    int ptile = blockIdx.x;                 // 0..3359
    int p  = ptile / NTILES_;
    int tl = ptile % NTILES_;
    int b = p / (C_ - 1);
    int c = p % (C_ - 1) + 1;
    int x0 = (tl % TILES_X_) * TS_;
    int y0 = (tl / TILES_X_) * TS_;
    for (int j = threadIdx.x; j < TS_ * TS_; j += 256) tile[j] = 0u;
    __syncthreads();
    int n = (int)cnt[ptile];
    if (n > CAP_) n = CAP_;
    const uint4* lst = lists + (size_t)ptile * CAP_;
    int wave = threadIdx.x >> 6, lane = threadIdx.x & 63;
    for (int r = wave; r < n; r += 4) {
        uint4 rec = lst[r];                 // broadcast within wave
        int i0 = (int)(rec.y & 0xFFu), i1 = (int)((rec.y >> 8) & 0xFFu);
        int i = i0 + lane;
        if (i <= i1) {
            float xs = (float)(rec.x & 0xFFFFu);
            float ys = (float)(rec.x >> 16);
            float dnx = __uint_as_float(rec.z);
            float dny = __uint_as_float(rec.w);
            float t = (float)(i + 1) * STEP_;
            float cx = __fadd_rn(xs, __fmul_rn(dnx, t));   // identical ops as pass A
            float cy = __fadd_rn(ys, __fmul_rn(dny, t));
            int lx = (int)rintf(cx) - x0;
            int ly = (int)rintf(cy) - y0;
            atomicAdd(&tile[ly * TS_ + lx], 1u);           // in-tile by construction
        }
    }
    __syncthreads();
    // scan: thread t owns 16 contiguous cells (row-major => idx order == global order)
    int start = threadIdx.x * 16;
    unsigned bv = tile[start];
    int bloc = start;
    #pragma unroll
    for (int j = 1; j < 16; ++j) {
        unsigned v = tile[start + j];
        if (v > bv) { bv = v; bloc = start + j; }
    }
    sv[threadIdx.x] = bv; si[threadIdx.x] = bloc;
    __syncthreads();
    for (int s = 128; s > 0; s >>= 1) {
        if (threadIdx.x < s) {
            unsigned ov = sv[threadIdx.x + s]; int oi = si[threadIdx.x + s];
            if (ov > sv[threadIdx.x] || (ov == sv[threadIdx.x] && oi < si[threadIdx.x])) {
                sv[threadIdx.x] = ov; si[threadIdx.x] = oi;
            }
        }
        __syncthreads();
    }
    if (threadIdx.x == 0) {
        int ly = si[0] >> 6, lx = si[0] & 63;
        unsigned gidx = (unsigned)((y0 + ly) * W_ + (x0 + lx));
        unsigned long long k = ((unsigned long long)sv[0] << 32)
                             | (unsigned long long)(0xFFFFFFFFu - gidx);
        atomicMax(&key[b * C_ + c], k);
    }
}

// -------- inlier z/count accumulation --------
__global__ __launch_bounds__(256) void inlier_kernel(const int* __restrict__ label,
                                                     const float* __restrict__ vp,
                                                     const unsigned long long* __restrict__ key,
                                                     float* __restrict__ z_sum,
                                                     float* __restrict__ n_inl) {
    __shared__ float zs[C_];
    __shared__ float ns[C_];
    const int bpb = P_ / 256;
    int b  = blockIdx.x / bpb;
    int pi = (blockIdx.x % bpb) * 256 + threadIdx.x;
    if (threadIdx.x < C_) { zs[threadIdx.x] = 0.0f; ns[threadIdx.x] = 0.0f; }
    __syncthreads();
    int idx = pi * SKIP_;
    int lab = label[b * HW_ + idx];
    if (lab > 0) {
        float ys = (float)(idx / W_);
        float xs = (float)(idx % W_);
        const float* s = vp + ((size_t)(b * HW_ + idx) * (C_ * 3)) + lab * 3;
        float dx = s[0], dy = s[1], z = s[2];
        float nrm = sqrtf(__fadd_rn(__fmul_rn(dx, dx), __fmul_rn(dy, dy))) + 1e-9f;
        float dnx = dx / nrm, dny = dy / nrm;
        unsigned long long k = key[b * C_ + lab];
        int pkv = (int)(0xFFFFFFFFu - (unsigned int)(k & 0xFFFFFFFFull));
        float pkx = (float)(pkv % W_), pky = (float)(pkv / W_);
        float dvx = __fsub_rn(pkx, xs), dvy = __fsub_rn(pky, ys);
        float nrm2 = sqrtf(__fadd_rn(__fmul_rn(dvx, dvx), __fmul_rn(dvy, dvy))) + 1e-9f;
        dvx /= nrm2; dvy /= nrm2;
        float dot = __fadd_rn(__fmul_rn(dnx, dvx), __fmul_rn(dny, dvy));
        if (dot > INL_T_) {
            atomicAdd(&zs[lab], z);
            atomicAdd(&ns[lab], 1.0f);
        }
    }
    __syncthreads();
    if (threadIdx.x < C_) {
        if (ns[threadIdx.x] != 0.0f) {
            atomicAdd(&z_sum[b * C_ + threadIdx.x], zs[threadIdx.x]);
            atomicAdd(&n_inl[b * C_ + threadIdx.x], ns[threadIdx.x]);
        }
    }
}

// -------- finalize rois + pose --------
__global__ __launch_bounds__(64) void finalize_kernel(const int* __restrict__ counts,
                                                      const unsigned long long* __restrict__ key,
                                                      const float* __restrict__ z_sum,
                                                      const float* __restrict__ n_inl,
                                                      const float* __restrict__ extents,
                                                      const float* __restrict__ meta,
                                                      float* __restrict__ out) {
    int t = threadIdx.x;
    if (t >= B_ * C_) return;
    int b = t / C_, c = t % C_;
    float* o = out + t * 14;
    bool valid = (counts[t] >= LAB_T_) && (c > 0);
    if (!valid) {
        #pragma unroll
        for (int k = 0; k < 14; ++k) o[k] = 0.0f;
        return;
    }
    float depth = z_sum[t] / fmaxf(n_inl[t], 1.0f);
    float z_safe = (fabsf(depth) > 0.001f) ? depth : 1.0f;
    float fx = meta[b * 48 + 0];
    float fy = meta[b * 48 + 4];
    const float* e = extents + c * 3;
    float diam = sqrtf(e[0]*e[0] + e[1]*e[1] + e[2]*e[2]);
    unsigned long long k = key[t];
    float vmax = (float)(unsigned int)(k >> 32);
    int pkv = (int)(0xFFFFFFFFu - (unsigned int)(k & 0xFFFFFFFFull));
    float pkx = (float)(pkv % W_), pky = (float)(pkv / W_);
    float half_w = ((0.5f * diam) * fx) / z_safe;
    float half_h = ((0.5f * diam) * fy) / z_safe;
    o[0] = (float)b;
    o[1] = (float)c;
    o[2] = pkx - half_w;
    o[3] = pky - half_h;
    o[4] = pkx + half_w;
    o[5] = pky + half_h;
    o[6] = vmax;
    const float* Ki = meta + b * 48 + 9;   // Kinv row-major 3x3
    float rx = Ki[0]*pkx + Ki[1]*pky + Ki[2];
    float ry = Ki[3]*pkx + Ki[4]*pky + Ki[5];
    float rz = Ki[6]*pkx + Ki[7]*pky + Ki[8];
    o[7]  = 1.0f;
    o[8]  = 0.0f;
    o[9]  = 0.0f;
    o[10] = 0.0f;
    o[11] = depth * rx;
    o[12] = depth * ry;
    o[13] = depth * rz;
}

extern "C" void kernel_launch(void* const* d_in, const int* in_sizes, int n_in,
                              void* d_out, int out_size, void* d_ws, size_t ws_size,
                              hipStream_t stream) {
    const int*   label   = (const int*)d_in[0];    // (B,H,W) int32
    const float* vp      = (const float*)d_in[1];  // (B,H,W,66) f32
    const float* extents = (const float*)d_in[2];  // (22,3) f32
    const float* meta    = (const float*)d_in[4];  // (B,48) f32
    float* out = (float*)d_out;                    // (B,C,14) = 616 f32

    char* ws = (char*)d_ws;
    size_t off = 0;
    unsigned int* cnt = (unsigned int*)(ws + off);          off += NPT_ * sizeof(unsigned int);      // 13440
    unsigned long long* key = (unsigned long long*)(ws + off); off += B_ * C_ * sizeof(unsigned long long);
    int*   counts = (int*)(ws + off);   off += B_ * C_ * sizeof(int);
    float* z_sum  = (float*)(ws + off); off += B_ * C_ * sizeof(float);
    float* n_inl  = (float*)(ws + off); off += B_ * C_ * sizeof(float);
    size_t zero_bytes = off;                                // ~14.3 KB, 16B-multiple
    uint4* lists = (uint4*)(ws + off);                      // 3360*1024*16B = 55 MB (uninitialized)

    hipMemsetAsync(d_ws, 0, zero_bytes, stream);

    binray_count_kernel<<<PA_BLOCKS_ + COUNT_BLOCKS_, 256, 0, stream>>>(label, vp, cnt, lists, counts);
    raster_argmax_kernel<<<NPT_, 256, 0, stream>>>(cnt, lists, key);
    inlier_kernel<<<(B_ * P_) / 256, 256, 0, stream>>>(label, vp, key, z_sum, n_inl);
    finalize_kernel<<<1, 64, 0, stream>>>(counts, key, z_sum, n_inl, extents, meta, out);
}